// Round 7
// baseline (183.170 us; speedup 1.0000x reference)
//
#include <hip/hip_runtime.h>
#include <stdint.h>

typedef short bf16x8 __attribute__((ext_vector_type(8)));
typedef float f32x4 __attribute__((ext_vector_type(4)));

#define NROWS 16384
#define K1DIM 256
#define N1DIM 2048
#define N2DIM 96
#define MARGIN 0.03f

#define GLD16(g, l) __builtin_amdgcn_global_load_lds( \
    (const __attribute__((address_space(1))) uint32_t*)(g), \
    (__attribute__((address_space(3))) uint32_t*)(l), 16, 0, 0)

__device__ __forceinline__ ushort f2bf(float x) {
  union { float f; uint32_t u; } c; c.f = x;
  uint32_t u = c.u;
  return (ushort)((u + 0x7FFFu + ((u >> 16) & 1u)) >> 16);
}

// ---------------- K0: convert inputs to bf16 (vectorized x2 path) ----------
__global__ __launch_bounds__(256) void k0_convert(
    const float* __restrict__ bd, const float* __restrict__ Wl1,
    const float* __restrict__ Wl2, const float* __restrict__ Wb1,
    ushort* __restrict__ x2bf, ushort* __restrict__ wl1t,
    ushort* __restrict__ w2t, ushort* __restrict__ wb1t) {
  int i = blockIdx.x * 256 + threadIdx.x;  // grid 4096 -> i < 1,048,576
  {
    float4 v = ((const float4*)bd)[i];
    ushort4 o;
    o.x = f2bf(v.x); o.y = f2bf(v.y); o.z = f2bf(v.z); o.w = f2bf(v.w);
    ((ushort4*)x2bf)[i] = o;
  }
  if (i < 2048 * 256) {  // wl1t[n][k] = Wl1[k][n]
    int n = i >> 8, k = i & 255;
    wl1t[i] = f2bf(Wl1[k * 2048 + n]);
  }
  if (i < 96 * 2048) {   // w2t[j][k] = Wl2[k][colmap(j)]
    int j = i >> 11, k = i & 2047;
    int col = (j < 48) ? j : (1440 + j);
    w2t[i] = f2bf(Wl2[k * 1536 + col]);
  }
  if (i < 512 * 128) {   // wb1t[j][m] = Wb1[m][j]
    int j = i >> 7, m = i & 127;
    wb1t[i] = f2bf(Wb1[m * 512 + j]);
  }
}

// ---------------- K1a: branch scores via bf16 MFMA -------------------------
__global__ __launch_bounds__(256) void k1a_score(
    const ushort* __restrict__ x2bf, const ushort* __restrict__ wb1t,
    const float* __restrict__ bb1, const float* __restrict__ Wb2,
    float* __restrict__ part) {
  __shared__ __align__(1024) ushort As[128 * 64];
  __shared__ __align__(1024) ushort Bs[128 * 64];
  const int t = threadIdx.x, ln = t & 63, wv = t >> 6;
  const int m0 = blockIdx.y << 7;
  const int n0 = blockIdx.x << 7;
  const int wm = (wv >> 1) << 6, wn = (wv & 1) << 6;
  const int rsub = ln >> 3, kc8 = ln & 7;
  const int q = ln >> 4, rr = ln & 15;

  f32x4 acc[4][4] = {};

  for (int k0 = 0; k0 < 128; k0 += 64) {
#pragma unroll
    for (int i = 0; i < 4; i++) {
      int inst = (wv << 2) + i;
      int row = (inst << 3) + rsub;
      GLD16(x2bf + (size_t)(m0 + row) * 256 + k0 + (kc8 << 3), As + (inst << 9));
      GLD16(wb1t + (size_t)(n0 + row) * 128 + k0 + (kc8 << 3), Bs + (inst << 9));
    }
    __syncthreads();
#pragma unroll
    for (int kk = 0; kk < 2; kk++) {
      int kb = ((kk << 2) + q) << 3;
      bf16x8 af[4], bfr[4];
#pragma unroll
      for (int mi = 0; mi < 4; mi++)
        af[mi] = *(const bf16x8*)(As + (((wm + (mi << 4) + rr)) << 6) + kb);
#pragma unroll
      for (int ni = 0; ni < 4; ni++)
        bfr[ni] = *(const bf16x8*)(Bs + (((wn + (ni << 4) + rr)) << 6) + kb);
#pragma unroll
      for (int mi = 0; mi < 4; mi++)
#pragma unroll
        for (int ni = 0; ni < 4; ni++)
          acc[mi][ni] = __builtin_amdgcn_mfma_f32_16x16x32_bf16(
              af[mi], bfr[ni], acc[mi][ni], 0, 0, 0);
    }
    __syncthreads();
  }

  float s4[4][4] = {};
#pragma unroll
  for (int ni = 0; ni < 4; ni++) {
    int col = n0 + wn + (ni << 4) + rr;
    float bias = bb1[col];
    float wdv = Wb2[col * 2 + 1] - Wb2[col * 2];
#pragma unroll
    for (int mi = 0; mi < 4; mi++) {
      f32x4 a = acc[mi][ni];
#pragma unroll
      for (int v = 0; v < 4; v++)
        s4[mi][v] += fmaxf(a[v] + bias, 0.f) * wdv;
    }
  }
#pragma unroll
  for (int off = 1; off <= 8; off <<= 1)
#pragma unroll
    for (int mi = 0; mi < 4; mi++)
#pragma unroll
      for (int v = 0; v < 4; v++)
        s4[mi][v] += __shfl_xor(s4[mi][v], off);

  if (rr == 0) {
    float* dst = part + (size_t)(blockIdx.x * 2 + (wv & 1)) * NROWS +
                 m0 + wm + (q << 2);
#pragma unroll
    for (int mi = 0; mi < 4; mi++) {
      float4 v4 = make_float4(s4[mi][0], s4[mi][1], s4[mi][2], s4[mi][3]);
      *(float4*)(dst + (mi << 4)) = v4;
    }
  }
}

// ---------------- K1b: sum partials, classify, compact marginal rows -------
__global__ __launch_bounds__(256) void k1b_classify(
    const float* __restrict__ part, const float* __restrict__ bb2,
    int* __restrict__ router, int* __restrict__ list, int* __restrict__ counter) {
  int t = blockIdx.x * 256 + threadIdx.x;
  float s = bb2[1] - bb2[0];
#pragma unroll
  for (int i = 0; i < 8; i++) s += part[i * NROWS + t];
  router[t] = (s >= 0.f) ? 1 : 0;
  if (fabsf(s) < MARGIN) {
    int idx = atomicAdd(counter, 1);
    list[idx] = t;
  }
}

// ---------------- K1c: exact fp32 recheck of marginal rows -----------------
__global__ __launch_bounds__(256) void k1c_recheck(
    const float* __restrict__ bd, const float* __restrict__ Wb1,
    const float* __restrict__ Wb2, const float* __restrict__ bb1,
    const float* __restrict__ bb2, const int* __restrict__ list,
    const int* __restrict__ counter, int* __restrict__ router) {
  const int ln = threadIdx.x & 63;
  const int wid = (blockIdx.x * 256 + threadIdx.x) >> 6;
  const int count = *counter;
  const float c = bb2[1] - bb2[0];

  for (int base = wid * 4; base < count; base += 512 * 4) {
    int rows[4];
#pragma unroll
    for (int r = 0; r < 4; r++) {
      int idx = base + r;
      rows[r] = list[(idx < count) ? idx : base];
    }
    float acc[4][8];
#pragma unroll
    for (int r = 0; r < 4; r++)
#pragma unroll
      for (int u = 0; u < 8; u++) acc[r][u] = 0.f;

    for (int m = 0; m < 128; m++) {
      float w[8];
#pragma unroll
      for (int u = 0; u < 8; u++) w[u] = Wb1[m * 512 + (u << 6) + ln];
#pragma unroll
      for (int r = 0; r < 4; r++) {
        float x = bd[(size_t)rows[r] * 256 + m];
#pragma unroll
        for (int u = 0; u < 8; u++) acc[r][u] = fmaf(x, w[u], acc[r][u]);
      }
    }
    float sc[4];
#pragma unroll
    for (int r = 0; r < 4; r++) {
      float s = 0.f;
#pragma unroll
      for (int u = 0; u < 8; u++) {
        int j = (u << 6) + ln;
        float wd = Wb2[j * 2 + 1] - Wb2[j * 2];
        s += fmaxf(acc[r][u] + bb1[j], 0.f) * wd;
      }
#pragma unroll
      for (int off = 1; off <= 32; off <<= 1) s += __shfl_xor(s, off);
      sc[r] = s + c;
    }
    if (ln == 0) {
#pragma unroll
      for (int r = 0; r < 4; r++)
        if (base + r < count) router[rows[r]] = (sc[r] >= 0.f) ? 1 : 0;
    }
  }
}

// ---------------- K2: FUSED, As staged once + B direct-from-L2 -------------
// block: 64 rows x 1024-col half, grid (2,256). As[64x256] staged ONCE.
// Per 256-col chunk: G1 barrier-free (A from LDS 4x-reuse, B frags direct
// global->VGPR, wave tile 64x64, acc 4x4). Then two 128-col halves:
// Hs write (owning waves) + Ws stage -> sync -> G2 (2x2 wave grid over
// P[64x96]) -> sync. 18 barriers/block total (was ~96).
__global__ __launch_bounds__(256, 2) void k2_fused(
    const ushort* __restrict__ x2bf, const ushort* __restrict__ wl1t,
    const ushort* __restrict__ w2t, const float* __restrict__ bl1,
    const float* __restrict__ bl2, const int* __restrict__ router,
    float* __restrict__ out) {
  __shared__ __align__(1024) ushort As[64 * 256];   // 32 KB, resident
  __shared__ __align__(1024) ushort Hs[64 * 128];   // 16 KB
  __shared__ __align__(1024) ushort Wsm[96 * 128];  // 24 KB
  const int t = threadIdx.x, ln = t & 63, wv = t >> 6;
  const int ks2 = blockIdx.x;       // n-half 0,1
  const int m0 = blockIdx.y << 6;   // 64-row block
  const int q = ln >> 4, rr = ln & 15;
  const int rg = wv & 1, cg = wv >> 1;  // G2 wave grid: row-group, col-group

  // stage As once: 32-slot XOR swizzle (slot s of row r holds chunk s^(r&31))
  {
    int s = ln & 31, rh = ln >> 5;
#pragma unroll
    for (int i = 0; i < 8; i++) {
      int inst = (wv << 3) + i;
      int r = (inst << 1) + rh;
      GLD16(x2bf + (size_t)(m0 + r) * 256 + ((s ^ (r & 31)) << 3),
            As + (inst << 9));
    }
  }
  __syncthreads();

  f32x4 accP[2][3] = {};

  for (int nc = 0; nc < 4; nc++) {
    const int n0 = (ks2 << 10) + (nc << 8);
    const int nw = n0 + (wv << 6);  // this wave's 64-col group

    // ---- G1: barrier-free. A: LDS (4x reuse). B: direct global (L2). ----
    f32x4 acc1[4][4] = {};
#pragma unroll 4
    for (int kk = 0; kk < 8; kk++) {
      bf16x8 bfr[4];
#pragma unroll
      for (int ni = 0; ni < 4; ni++)
        bfr[ni] = *(const bf16x8*)(wl1t + (size_t)(nw + (ni << 4) + rr) * 256 +
                                   (kk << 5) + (q << 3));
      bf16x8 af[4];
#pragma unroll
      for (int mi = 0; mi < 4; mi++) {
        int row = (mi << 4) + rr;
        af[mi] = *(const bf16x8*)(As + (row << 8) +
                                  ((((kk << 2) + q) ^ (row & 31)) << 3));
      }
#pragma unroll
      for (int mi = 0; mi < 4; mi++)
#pragma unroll
        for (int ni = 0; ni < 4; ni++)
          acc1[mi][ni] = __builtin_amdgcn_mfma_f32_16x16x32_bf16(
              af[mi], bfr[ni], acc1[mi][ni], 0, 0, 0);
    }

    // ---- two 128-col halves: Hs/Ws stage -> G2 ----
#pragma unroll 1
    for (int h = 0; h < 2; h++) {
      // stage Ws[96][128] for k-cols n0+h*128 (slot s holds chunk s^(r&15))
#pragma unroll
      for (int j = 0; j < 6; j++) {
        int inst = wv * 6 + j;
        int r = (inst << 2) + q;
        GLD16(w2t + (size_t)r * 2048 + n0 + (h << 7) + ((rr ^ (r & 15)) << 3),
              Wsm + (inst << 9));
      }
      // owning waves (cols in this half) write bias+relu'd acc1 into Hs
      if ((wv >> 1) == h) {
#pragma unroll
        for (int ni = 0; ni < 4; ni++) {
          int colh = ((wv & 1) << 6) + (ni << 4) + rr;
          float bias = bl1[nw + (ni << 4) + rr];
#pragma unroll
          for (int mi = 0; mi < 4; mi++) {
            f32x4 a = acc1[mi][ni];
#pragma unroll
            for (int v = 0; v < 4; v++) {
              int row = (mi << 4) + (q << 2) + v;
              Hs[(row << 7) + (((colh >> 3) ^ (row & 15)) << 3) + (colh & 7)] =
                  f2bf(fmaxf(a[v] + bias, 0.f));
            }
          }
        }
      }
      __syncthreads();
      // G2: wave (rg,cg) computes rows rg*32..+31 x cols cg*48..+47
#pragma unroll
      for (int kk = 0; kk < 4; kk++) {
        int c = (kk << 2) + q;
        bf16x8 ha[2];
#pragma unroll
        for (int a = 0; a < 2; a++) {
          int row = (rg << 5) + (a << 4) + rr;
          ha[a] = *(const bf16x8*)(Hs + (row << 7) + ((c ^ rr) << 3));
        }
#pragma unroll
        for (int ni = 0; ni < 3; ni++) {
          int jr = cg * 48 + (ni << 4) + rr;
          bf16x8 wb = *(const bf16x8*)(Wsm + (jr << 7) + ((c ^ rr) << 3));
#pragma unroll
          for (int a = 0; a < 2; a++)
            accP[a][ni] = __builtin_amdgcn_mfma_f32_16x16x32_bf16(
                ha[a], wb, accP[a][ni], 0, 0, 0);
        }
      }
      __syncthreads();
    }
  }

  // ---- select epilogue: only the col-group matching router[row] writes ----
#pragma unroll
  for (int a = 0; a < 2; a++) {
#pragma unroll
    for (int v = 0; v < 4; v++) {
      int row = m0 + (rg << 5) + (a << 4) + (q << 2) + v;
      int sel = router[row];
      if (sel == cg) {
        float b0 = 0.f, b1 = 0.f, b2 = 0.f;
        if (ks2 == 0) {  // bias added exactly once
          int bb = sel ? 1488 : 0;
          b0 = bl2[bb + rr];
          b1 = bl2[bb + 16 + rr];
          b2 = bl2[bb + 32 + rr];
        }
        float* ob = out + (size_t)row * 48 + rr;
        atomicAdd(ob, accP[a][0][v] + b0);
        atomicAdd(ob + 16, accP[a][1][v] + b1);
        atomicAdd(ob + 32, accP[a][2][v] + b2);
      }
    }
  }
}

extern "C" void kernel_launch(void* const* d_in, const int* in_sizes, int n_in,
                              void* d_out, int out_size, void* d_ws, size_t ws_size,
                              hipStream_t stream) {
  const float* bd  = (const float*)d_in[0];
  const float* Wl1 = (const float*)d_in[1];
  const float* bl1 = (const float*)d_in[2];
  const float* Wl2 = (const float*)d_in[3];
  const float* bl2 = (const float*)d_in[4];
  const float* Wb1 = (const float*)d_in[5];
  const float* bb1 = (const float*)d_in[6];
  const float* Wb2 = (const float*)d_in[7];
  const float* bb2 = (const float*)d_in[8];

  char* ws = (char*)d_ws;
  ushort* x2bf  = (ushort*)(ws);                  // 16384*256*2  = 8,388,608
  ushort* wl1t  = (ushort*)(ws + 8388608);        // 2048*256*2   = 1,048,576
  ushort* w2t   = (ushort*)(ws + 9437184);        // 96*2048*2    =   393,216
  int*    router= (int*)(ws + 89522176);          // 16384*4
  ushort* wb1t  = (ushort*)(ws + 89587712);       // 512*128*2
  float*  part  = (float*)(ws + 89718784);        // 8*16384*4
  int*    list  = (int*)(ws + 90243072);          // 16384*4
  int*    counter=(int*)(ws + 90308608);          // 4
  float*  outp  = (float*)d_out;

  k0_convert<<<dim3(4096), dim3(256), 0, stream>>>(bd, Wl1, Wl2, Wb1,
                                                   x2bf, wl1t, w2t, wb1t);
  hipMemsetAsync(counter, 0, 4, stream);
  hipMemsetAsync(outp, 0, (size_t)out_size * 4, stream);
  k1a_score<<<dim3(4, 128), dim3(256), 0, stream>>>(x2bf, wb1t, bb1, Wb2, part);
  k1b_classify<<<dim3(64), dim3(256), 0, stream>>>(part, bb2, router, list, counter);
  k1c_recheck<<<dim3(128), dim3(256), 0, stream>>>(bd, Wb1, Wb2, bb1, bb2,
                                                   list, counter, router);
  k2_fused<<<dim3(2, 256), dim3(256), 0, stream>>>(x2bf, wl1t, w2t, bl1, bl2,
                                                   router, outp);
}

// Round 8
// 180.007 us; speedup vs baseline: 1.0176x; 1.0176x over previous
//
#include <hip/hip_runtime.h>
#include <stdint.h>

typedef short bf16x8 __attribute__((ext_vector_type(8)));
typedef float f32x4 __attribute__((ext_vector_type(4)));

#define NROWS 16384
#define NSLOTS 16448   // NROWS + 64 gap
#define K1DIM 256
#define N1DIM 2048
#define MARGIN 0.03f

#define GLD16(g, l) __builtin_amdgcn_global_load_lds( \
    (const __attribute__((address_space(1))) uint32_t*)(g), \
    (__attribute__((address_space(3))) uint32_t*)(l), 16, 0, 0)

__device__ __forceinline__ ushort f2bf(float x) {
  union { float f; uint32_t u; } c; c.f = x;
  uint32_t u = c.u;
  return (ushort)((u + 0x7FFFu + ((u >> 16) & 1u)) >> 16);
}

// ---------------- K0: convert inputs to bf16 -------------------------------
__global__ __launch_bounds__(256) void k0_convert(
    const float* __restrict__ bd, const float* __restrict__ Wl1,
    const float* __restrict__ Wl2, const float* __restrict__ Wb1,
    ushort* __restrict__ x2bf, ushort* __restrict__ wl1t,
    ushort* __restrict__ w2t, ushort* __restrict__ wb1t) {
  int i = blockIdx.x * 256 + threadIdx.x;  // grid 4096
  {
    float4 v = ((const float4*)bd)[i];
    ushort4 o;
    o.x = f2bf(v.x); o.y = f2bf(v.y); o.z = f2bf(v.z); o.w = f2bf(v.w);
    ((ushort4*)x2bf)[i] = o;
  }
  if (i < 2048 * 256) {  // wl1t[n][k] = Wl1[k][n]
    int n = i >> 8, k = i & 255;
    wl1t[i] = f2bf(Wl1[k * 2048 + n]);
  }
  if (i < 96 * 2048) {   // w2t[j][k] = Wl2[k][colmap(j)]
    int j = i >> 11, k = i & 2047;
    int col = (j < 48) ? j : (1440 + j);
    w2t[i] = f2bf(Wl2[k * 1536 + col]);
  }
  if (i < 512 * 128) {   // wb1t[j][m] = Wb1[m][j]
    int j = i >> 7, m = i & 127;
    wb1t[i] = f2bf(Wb1[m * 512 + j]);
  }
}

// ---------------- K1a: branch scores via bf16 MFMA -------------------------
__global__ __launch_bounds__(256) void k1a_score(
    const ushort* __restrict__ x2bf, const ushort* __restrict__ wb1t,
    const float* __restrict__ bb1, const float* __restrict__ Wb2,
    float* __restrict__ part) {
  __shared__ __align__(1024) ushort As[128 * 64];
  __shared__ __align__(1024) ushort Bs[128 * 64];
  const int t = threadIdx.x, ln = t & 63, wv = t >> 6;
  const int m0 = blockIdx.y << 7;
  const int n0 = blockIdx.x << 7;
  const int wm = (wv >> 1) << 6, wn = (wv & 1) << 6;
  const int rsub = ln >> 3, kc8 = ln & 7;
  const int q = ln >> 4, rr = ln & 15;

  f32x4 acc[4][4] = {};

  for (int k0 = 0; k0 < 128; k0 += 64) {
#pragma unroll
    for (int i = 0; i < 4; i++) {
      int inst = (wv << 2) + i;
      int row = (inst << 3) + rsub;
      GLD16(x2bf + (size_t)(m0 + row) * 256 + k0 + (kc8 << 3), As + (inst << 9));
      GLD16(wb1t + (size_t)(n0 + row) * 128 + k0 + (kc8 << 3), Bs + (inst << 9));
    }
    __syncthreads();
#pragma unroll
    for (int kk = 0; kk < 2; kk++) {
      int kb = ((kk << 2) + q) << 3;
      bf16x8 af[4], bfr[4];
#pragma unroll
      for (int mi = 0; mi < 4; mi++)
        af[mi] = *(const bf16x8*)(As + (((wm + (mi << 4) + rr)) << 6) + kb);
#pragma unroll
      for (int ni = 0; ni < 4; ni++)
        bfr[ni] = *(const bf16x8*)(Bs + (((wn + (ni << 4) + rr)) << 6) + kb);
#pragma unroll
      for (int mi = 0; mi < 4; mi++)
#pragma unroll
        for (int ni = 0; ni < 4; ni++)
          acc[mi][ni] = __builtin_amdgcn_mfma_f32_16x16x32_bf16(
              af[mi], bfr[ni], acc[mi][ni], 0, 0, 0);
    }
    __syncthreads();
  }

  float s4[4][4] = {};
#pragma unroll
  for (int ni = 0; ni < 4; ni++) {
    int col = n0 + wn + (ni << 4) + rr;
    float bias = bb1[col];
    float wdv = Wb2[col * 2 + 1] - Wb2[col * 2];
#pragma unroll
    for (int mi = 0; mi < 4; mi++) {
      f32x4 a = acc[mi][ni];
#pragma unroll
      for (int v = 0; v < 4; v++)
        s4[mi][v] += fmaxf(a[v] + bias, 0.f) * wdv;
    }
  }
#pragma unroll
  for (int off = 1; off <= 8; off <<= 1)
#pragma unroll
    for (int mi = 0; mi < 4; mi++)
#pragma unroll
      for (int v = 0; v < 4; v++)
        s4[mi][v] += __shfl_xor(s4[mi][v], off);

  if (rr == 0) {
    float* dst = part + (size_t)(blockIdx.x * 2 + (wv & 1)) * NROWS +
                 m0 + wm + (q << 2);
#pragma unroll
    for (int mi = 0; mi < 4; mi++) {
      float4 v4 = make_float4(s4[mi][0], s4[mi][1], s4[mi][2], s4[mi][3]);
      *(float4*)(dst + (mi << 4)) = v4;
    }
  }
}

// ---------------- K1b: sum partials, classify, compact marginal rows -------
__global__ __launch_bounds__(256) void k1b_classify(
    const float* __restrict__ part, const float* __restrict__ bb2,
    int* __restrict__ router, int* __restrict__ list, int* __restrict__ counters) {
  int t = blockIdx.x * 256 + threadIdx.x;
  float s = bb2[1] - bb2[0];
#pragma unroll
  for (int i = 0; i < 8; i++) s += part[i * NROWS + t];
  router[t] = (s >= 0.f) ? 1 : 0;
  if (fabsf(s) < MARGIN) {
    int idx = atomicAdd(&counters[0], 1);
    list[idx] = t;
  }
}

// ---------------- K1c: exact fp32 recheck of marginal rows -----------------
__global__ __launch_bounds__(256) void k1c_recheck(
    const float* __restrict__ bd, const float* __restrict__ Wb1,
    const float* __restrict__ Wb2, const float* __restrict__ bb1,
    const float* __restrict__ bb2, const int* __restrict__ list,
    const int* __restrict__ counters, int* __restrict__ router) {
  const int ln = threadIdx.x & 63;
  const int wid = (blockIdx.x * 256 + threadIdx.x) >> 6;
  const int count = counters[0];
  const float c = bb2[1] - bb2[0];

  for (int base = wid * 4; base < count; base += 512 * 4) {
    int rows[4];
#pragma unroll
    for (int r = 0; r < 4; r++) {
      int idx = base + r;
      rows[r] = list[(idx < count) ? idx : base];
    }
    float acc[4][8];
#pragma unroll
    for (int r = 0; r < 4; r++)
#pragma unroll
      for (int u = 0; u < 8; u++) acc[r][u] = 0.f;

    for (int m = 0; m < 128; m++) {
      float w[8];
#pragma unroll
      for (int u = 0; u < 8; u++) w[u] = Wb1[m * 512 + (u << 6) + ln];
#pragma unroll
      for (int r = 0; r < 4; r++) {
        float x = bd[(size_t)rows[r] * 256 + m];
#pragma unroll
        for (int u = 0; u < 8; u++) acc[r][u] = fmaf(x, w[u], acc[r][u]);
      }
    }
    float sc[4];
#pragma unroll
    for (int r = 0; r < 4; r++) {
      float s = 0.f;
#pragma unroll
      for (int u = 0; u < 8; u++) {
        int j = (u << 6) + ln;
        float wd = Wb2[j * 2 + 1] - Wb2[j * 2];
        s += fmaxf(acc[r][u] + bb1[j], 0.f) * wd;
      }
#pragma unroll
      for (int off = 1; off <= 32; off <<= 1) s += __shfl_xor(s, off);
      sc[r] = s + c;
    }
    if (ln == 0) {
#pragma unroll
      for (int r = 0; r < 4; r++)
        if (base + r < count) router[rows[r]] = (sc[r] >= 0.f) ? 1 : 0;
    }
  }
}

// ---------------- K1d: build partitioned rowmap ----------------------------
// sel0 rows fill slots from the front, sel1 from the back of 16448; the 64
// unfilled middle slots stay -1 (pads) -> every 64-row block is leaf-pure.
__global__ __launch_bounds__(256) void k1d_rowmap(
    const int* __restrict__ router, int* __restrict__ rowmap,
    int* __restrict__ counters) {
  int t = blockIdx.x * 256 + threadIdx.x;
  int sel = router[t];
  int slot = sel ? (NSLOTS - 1 - atomicAdd(&counters[2], 1))
                 : atomicAdd(&counters[1], 1);
  rowmap[slot] = t;
}

// ---------------- K2: FUSED, partitioned rows, swapped-operand G1 ----------
// block: 64 row-slots x 1024-col half, grid (2,257). Per 256-col chunk:
//   G1 (swapped): Ht = Wl1t-tile @ x2-tile -> lane holds 4 consecutive H-cols
//   -> 16 ds_write_b64 into Hs (aliased on Wt). G2: 48 cols only (leaf-pure).
__global__ __launch_bounds__(256, 3) void k2_fused(
    const ushort* __restrict__ x2bf, const ushort* __restrict__ wl1t,
    const ushort* __restrict__ w2t, const float* __restrict__ bl1,
    const float* __restrict__ bl2, const int* __restrict__ rowmap,
    const int* __restrict__ counters, float* __restrict__ out) {
  __shared__ __align__(1024) ushort As[4096];     // x2 [64 r][64 k] / kstep, 8K
  __shared__ __align__(1024) ushort WtHs[16384];  // Wt[256][64] <-> Hs[64][256], 32K
  __shared__ __align__(1024) ushort Ws[6144];     // W2 [48][128 half], 12K
  ushort* Wt = WtHs;
  ushort* Hs = WtHs;
  const int t = threadIdx.x, ln = t & 63, wv = t >> 6;
  const int ks2 = blockIdx.x;       // n-half 0,1
  const int m0 = blockIdx.y << 6;   // 64 slot-base
  const int q = ln >> 4, rr = ln & 15;
  const int r8 = ln >> 3, s8 = ln & 7;
  const int r4 = ln >> 4, s16 = ln & 15;
  const int c0 = counters[1];
  const int sel_blk = (m0 >= c0) ? 1 : 0;
  const int selbase = sel_blk * 48;

  // gather indices for As staging (2 insts/wave, fixed rows per lane)
  int g_as[2];
#pragma unroll
  for (int ii = 0; ii < 2; ii++) {
    int g = rowmap[m0 + (((wv << 1) + ii) << 3) + r8];
    g_as[ii] = (g < 0) ? 0 : g;
  }

  f32x4 accP[3] = {};

  for (int nc = 0; nc < 4; nc++) {
    const int n0 = (ks2 << 10) + (nc << 8);

    // ---- G1: Ht[256 cols x 64 rows] over K=256, 4 k64-steps ----
    f32x4 acc1[4][4] = {};
#pragma unroll 1
    for (int ks = 0; ks < 4; ks++) {
      const int kg = ks << 6;
#pragma unroll
      for (int ii = 0; ii < 2; ii++)
        GLD16(x2bf + (size_t)g_as[ii] * 256 + kg + ((s8 ^ r8) << 3),
              As + ((((wv << 1) + ii)) << 9));
#pragma unroll
      for (int ii = 0; ii < 8; ii++) {
        int inst = (wv << 3) + ii;
        int r = (inst << 3) + r8;
        GLD16(wl1t + (size_t)(n0 + r) * 256 + kg + ((s8 ^ r8) << 3),
              Wt + (inst << 9));
      }
      __syncthreads();
#pragma unroll
      for (int kk = 0; kk < 2; kk++) {
        int c = (kk << 2) + q;
        int sl = (c ^ (rr & 7)) << 3;
        bf16x8 af[4], bfv[4];
#pragma unroll
        for (int mi = 0; mi < 4; mi++)
          af[mi] = *(const bf16x8*)(Wt + (((wv << 6) + (mi << 4) + rr) << 6) + sl);
#pragma unroll
        for (int ni = 0; ni < 4; ni++)
          bfv[ni] = *(const bf16x8*)(As + (((ni << 4) + rr) << 6) + sl);
#pragma unroll
        for (int mi = 0; mi < 4; mi++)
#pragma unroll
          for (int ni = 0; ni < 4; ni++)
            acc1[mi][ni] = __builtin_amdgcn_mfma_f32_16x16x32_bf16(
                af[mi], bfv[ni], acc1[mi][ni], 0, 0, 0);
      }
      __syncthreads();
    }

    // ---- Hs write: lane holds 4 consecutive H-cols of one x2-row ----
    // D[m=H-col][n=x2-row]: col n = rr, rows m = q*4+v
#pragma unroll
    for (int mi = 0; mi < 4; mi++) {
      int p = (wv << 4) + (mi << 2) + q;  // 4-col pack index 0..63
      float bias0 = bl1[n0 + (p << 2) + 0];
      float bias1 = bl1[n0 + (p << 2) + 1];
      float bias2 = bl1[n0 + (p << 2) + 2];
      float bias3 = bl1[n0 + (p << 2) + 3];
#pragma unroll
      for (int ni = 0; ni < 4; ni++) {
        int hsrow = (ni << 4) + rr;
        f32x4 a = acc1[mi][ni];
        ushort4 pk;
        pk.x = f2bf(fmaxf(a[0] + bias0, 0.f));
        pk.y = f2bf(fmaxf(a[1] + bias1, 0.f));
        pk.z = f2bf(fmaxf(a[2] + bias2, 0.f));
        pk.w = f2bf(fmaxf(a[3] + bias3, 0.f));
        *(ushort4*)(Hs + (hsrow << 8) + ((p ^ rr) << 2)) = pk;
      }
    }

    // ---- G2 in two 128-col halves (Ws staged per half, 48 cols only) ----
#pragma unroll 1
    for (int h = 0; h < 2; h++) {
#pragma unroll
      for (int jj = 0; jj < 3; jj++) {
        int inst = wv * 3 + jj;            // 0..11, 4 rows each
        int r = (inst << 2) + r4;
        int c = s16 ^ (r & 15);
        GLD16(w2t + (size_t)(selbase + r) * 2048 + n0 + (h << 7) + (c << 3),
              Ws + (inst << 9));
      }
      __syncthreads();
#pragma unroll
      for (int kk = 0; kk < 4; kk++) {
        int p0 = (h << 5) + (kk << 3) + (q << 1);
        int hrow = (wv << 4) + rr;
        union { ushort4 u[2]; bf16x8 v; } hu;
        hu.u[0] = *(const ushort4*)(Hs + (hrow << 8) + ((p0 ^ rr) << 2));
        hu.u[1] = *(const ushort4*)(Hs + (hrow << 8) + (((p0 + 1) ^ rr) << 2));
        int c = (kk << 2) + q;
#pragma unroll
        for (int ni = 0; ni < 3; ni++) {
          bf16x8 wb = *(const bf16x8*)(Ws + (((ni << 4) + rr) << 7) +
                                       ((c ^ rr) << 3));
          accP[ni] = __builtin_amdgcn_mfma_f32_16x16x32_bf16(
              hu.v, wb, accP[ni], 0, 0, 0);
        }
      }
      __syncthreads();
    }
  }

  // ---- epilogue: wave owns slot-rows m0+wv*16+q*4+v; scatter to out ----
  {
    float b[3] = {0.f, 0.f, 0.f};
    if (ks2 == 0) {
#pragma unroll
      for (int ni = 0; ni < 3; ni++)
        b[ni] = bl2[sel_blk * 1488 + (ni << 4) + rr];
    }
#pragma unroll
    for (int v = 0; v < 4; v++) {
      int slot = m0 + (wv << 4) + (q << 2) + v;
      int orig = rowmap[slot];
      if (orig >= 0) {
        float* ob = out + (size_t)orig * 48 + rr;
        atomicAdd(ob, accP[0][v] + b[0]);
        atomicAdd(ob + 16, accP[1][v] + b[1]);
        atomicAdd(ob + 32, accP[2][v] + b[2]);
      }
    }
  }
}

extern "C" void kernel_launch(void* const* d_in, const int* in_sizes, int n_in,
                              void* d_out, int out_size, void* d_ws, size_t ws_size,
                              hipStream_t stream) {
  const float* bd  = (const float*)d_in[0];
  const float* Wl1 = (const float*)d_in[1];
  const float* bl1 = (const float*)d_in[2];
  const float* Wl2 = (const float*)d_in[3];
  const float* bl2 = (const float*)d_in[4];
  const float* Wb1 = (const float*)d_in[5];
  const float* bb1 = (const float*)d_in[6];
  const float* Wb2 = (const float*)d_in[7];
  const float* bb2 = (const float*)d_in[8];

  char* ws = (char*)d_ws;
  ushort* x2bf  = (ushort*)(ws);                  // 16384*256*2  = 8,388,608
  ushort* wl1t  = (ushort*)(ws + 8388608);        // 2048*256*2   = 1,048,576
  ushort* w2t   = (ushort*)(ws + 9437184);        // 96*2048*2    =   393,216
  int*    router= (int*)(ws + 89522176);          // 16384*4
  ushort* wb1t  = (ushort*)(ws + 89587712);       // 512*128*2
  float*  part  = (float*)(ws + 89718784);        // 8*16384*4
  int*    list  = (int*)(ws + 90243072);          // 16384*4
  int*    counters=(int*)(ws + 90308608);         // 3*4
  int*    rowmap= (int*)(ws + 90310656);          // 16448*4 = 65,792
  float*  outp  = (float*)d_out;

  k0_convert<<<dim3(4096), dim3(256), 0, stream>>>(bd, Wl1, Wl2, Wb1,
                                                   x2bf, wl1t, w2t, wb1t);
  hipMemsetAsync(counters, 0, 12, stream);
  hipMemsetAsync(rowmap, 0xFF, NSLOTS * 4, stream);
  hipMemsetAsync(outp, 0, (size_t)out_size * 4, stream);
  k1a_score<<<dim3(4, 128), dim3(256), 0, stream>>>(x2bf, wb1t, bb1, Wb2, part);
  k1b_classify<<<dim3(64), dim3(256), 0, stream>>>(part, bb2, router, list,
                                                   counters);
  k1c_recheck<<<dim3(128), dim3(256), 0, stream>>>(bd, Wb1, Wb2, bb1, bb2,
                                                   list, counters, router);
  k1d_rowmap<<<dim3(64), dim3(256), 0, stream>>>(router, rowmap, counters);
  k2_fused<<<dim3(2, 257), dim3(256), 0, stream>>>(x2bf, wl1t, w2t, bl1, bl2,
                                                   rowmap, counters, outp);
}

// Round 9
// 158.338 us; speedup vs baseline: 1.1568x; 1.1369x over previous
//
#include <hip/hip_runtime.h>
#include <stdint.h>

typedef short bf16x8 __attribute__((ext_vector_type(8)));
typedef float f32x4 __attribute__((ext_vector_type(4)));

#define NROWS 16384
#define NSLOTS 16448   // NROWS + 64 gap
#define K1DIM 256
#define MARGIN2 2e-3f

#define GLD16(g, l) __builtin_amdgcn_global_load_lds( \
    (const __attribute__((address_space(1))) uint32_t*)(g), \
    (__attribute__((address_space(3))) uint32_t*)(l), 16, 0, 0)

__device__ __forceinline__ ushort f2bf(float x) {
  union { float f; uint32_t u; } c; c.f = x;
  uint32_t u = c.u;
  return (ushort)((u + 0x7FFFu + ((u >> 16) & 1u)) >> 16);
}
__device__ __forceinline__ float bf2f(ushort h) {
  union { float f; uint32_t u; } c; c.u = ((uint32_t)h) << 16;
  return c.f;
}

// ---------------- K0: convert + hi/lo splits + all buffer inits ------------
__global__ __launch_bounds__(256) void k0_convert(
    const float* __restrict__ bd, const float* __restrict__ Wl1,
    const float* __restrict__ Wl2, const float* __restrict__ Wb1,
    ushort* __restrict__ x2bf, ushort* __restrict__ wl1t,
    ushort* __restrict__ w2t, ushort* __restrict__ wb1t,
    ushort* __restrict__ wb1lo, ushort* __restrict__ x1lo,
    int* __restrict__ rowmap, int* __restrict__ counters,
    float* __restrict__ out) {
  int i = blockIdx.x * 256 + threadIdx.x;  // grid 4096 -> 1,048,576 threads
  {
    float4 v = ((const float4*)bd)[i];
    ushort4 o;
    o.x = f2bf(v.x); o.y = f2bf(v.y); o.z = f2bf(v.z); o.w = f2bf(v.w);
    ((ushort4*)x2bf)[i] = o;
  }
  if (i < 524288) {  // x1lo: lo-residual of main-cam cols (first 128 of 256)
    int r = i >> 5, c = i & 31;
    float4 v = ((const float4*)bd)[(r << 6) + c];
    ushort4 h, l;
    h.x = f2bf(v.x); h.y = f2bf(v.y); h.z = f2bf(v.z); h.w = f2bf(v.w);
    l.x = f2bf(v.x - bf2f(h.x)); l.y = f2bf(v.y - bf2f(h.y));
    l.z = f2bf(v.z - bf2f(h.z)); l.w = f2bf(v.w - bf2f(h.w));
    ((ushort4*)x1lo)[i] = l;
  }
  if (i < 2048 * 256) {  // wl1t[n][k] = Wl1[k][n]
    int n = i >> 8, k = i & 255;
    wl1t[i] = f2bf(Wl1[k * 2048 + n]);
  }
  if (i < 96 * 2048) {   // w2t[j][k] = Wl2[k][colmap(j)]
    int j = i >> 11, k = i & 2047;
    int col = (j < 48) ? j : (1440 + j);
    w2t[i] = f2bf(Wl2[k * 1536 + col]);
  }
  if (i < 512 * 128) {   // wb1t/wb1lo [j][m] = hi/lo of Wb1[m][j]
    int j = i >> 7, m = i & 127;
    float w = Wb1[m * 512 + j];
    ushort h = f2bf(w);
    wb1t[i] = h;
    wb1lo[i] = f2bf(w - bf2f(h));
  }
  if (i < 196608) ((float4*)out)[i] = make_float4(0.f, 0.f, 0.f, 0.f);
  if (i < NSLOTS) rowmap[i] = -1;
  if (i < 8) counters[i] = 0;
}

// ---------------- K1: FUSED router (score + recheck + rowmap) --------------
// 256 blocks x 64 rows. Scores via hi/lo-split bf16 MFMA (err ~1e-4);
// |s| < 2e-3 rows re-checked in-block in exact fp32; rowmap built inline.
__global__ __launch_bounds__(256) void k1_router(
    const ushort* __restrict__ x2bf, const ushort* __restrict__ x1lo,
    const ushort* __restrict__ wb1t, const ushort* __restrict__ wb1lo,
    const float* __restrict__ bd, const float* __restrict__ Wb1,
    const float* __restrict__ Wb2, const float* __restrict__ bb1,
    const float* __restrict__ bb2, int* __restrict__ rowmap,
    int* __restrict__ counters) {
  __shared__ __align__(1024) ushort Xh[64 * 128];   // 16 KB
  __shared__ __align__(1024) ushort Xl[64 * 128];   // 16 KB
  __shared__ __align__(1024) ushort Wh[128 * 128];  // 32 KB
  __shared__ __align__(1024) ushort Wl[128 * 128];  // 32 KB
  __shared__ float red[256];
  __shared__ float scores[64];
  __shared__ float redw[4];
  __shared__ int mlist[64];
  __shared__ int nmarg;
  const int t = threadIdx.x, ln = t & 63, wv = t >> 6;
  const int m0 = blockIdx.x << 6;
  const int q = ln >> 4, rr = ln & 15;

  if (t == 0) nmarg = 0;

  // stage X hi/lo (main cam = cols 0..127 of x2bf rows): 16 insts each, 4/wave
#pragma unroll
  for (int ii = 0; ii < 4; ii++) {
    int inst = (wv << 2) + ii;
    int r = (inst << 2) + q;
    int sl = (rr ^ (r & 15)) << 3;
    GLD16(x2bf + (size_t)(m0 + r) * 256 + sl, Xh + (inst << 9));
    GLD16(x1lo + (size_t)(m0 + r) * 128 + sl, Xl + (inst << 9));
  }

  float s4[4][4];
#pragma unroll
  for (int a = 0; a < 4; a++)
#pragma unroll
    for (int b = 0; b < 4; b++) s4[a][b] = 0.f;

  for (int nc = 0; nc < 4; nc++) {
    // stage W hi/lo 128-col chunk: 32 insts each, 8/wave
#pragma unroll
    for (int ii = 0; ii < 8; ii++) {
      int inst = (wv << 3) + ii;
      int jr = (inst << 2) + q;
      int jg = (nc << 7) + jr;
      int sl = (rr ^ (jr & 15)) << 3;
      GLD16(wb1t + (size_t)jg * 128 + sl, Wh + (inst << 9));
      GLD16(wb1lo + (size_t)jg * 128 + sl, Wl + (inst << 9));
    }
    __syncthreads();

    f32x4 acc[4][2] = {};
#pragma unroll
    for (int kk = 0; kk < 4; kk++) {
      int c = (kk << 2) + q;
      bf16x8 xh[4], xl[4], wh[2], wlv[2];
#pragma unroll
      for (int mi = 0; mi < 4; mi++) {
        int row = (mi << 4) + rr;
        int sl = (c ^ rr) << 3;
        xh[mi] = *(const bf16x8*)(Xh + (row << 7) + sl);
        xl[mi] = *(const bf16x8*)(Xl + (row << 7) + sl);
      }
#pragma unroll
      for (int ni = 0; ni < 2; ni++) {
        int row = (wv << 5) + (ni << 4) + rr;
        int sl = (c ^ rr) << 3;
        wh[ni] = *(const bf16x8*)(Wh + (row << 7) + sl);
        wlv[ni] = *(const bf16x8*)(Wl + (row << 7) + sl);
      }
#pragma unroll
      for (int mi = 0; mi < 4; mi++)
#pragma unroll
        for (int ni = 0; ni < 2; ni++) {
          acc[mi][ni] = __builtin_amdgcn_mfma_f32_16x16x32_bf16(
              xh[mi], wh[ni], acc[mi][ni], 0, 0, 0);
          acc[mi][ni] = __builtin_amdgcn_mfma_f32_16x16x32_bf16(
              xh[mi], wlv[ni], acc[mi][ni], 0, 0, 0);
          acc[mi][ni] = __builtin_amdgcn_mfma_f32_16x16x32_bf16(
              xl[mi], wh[ni], acc[mi][ni], 0, 0, 0);
        }
    }
    __syncthreads();  // MFMA reads done before next chunk's staging

    // epilogue: relu + dot with wd, accumulate per-row partials
#pragma unroll
    for (int ni = 0; ni < 2; ni++) {
      int j = (nc << 7) + (wv << 5) + (ni << 4) + rr;
      float bias = bb1[j];
      float wd = Wb2[j * 2 + 1] - Wb2[j * 2];
#pragma unroll
      for (int mi = 0; mi < 4; mi++) {
        f32x4 a = acc[mi][ni];
#pragma unroll
        for (int v = 0; v < 4; v++)
          s4[mi][v] += fmaxf(a[v] + bias, 0.f) * wd;
      }
    }
  }

  // reduce over the 16 rr-lanes, then across waves via LDS
#pragma unroll
  for (int off = 1; off <= 8; off <<= 1)
#pragma unroll
    for (int mi = 0; mi < 4; mi++)
#pragma unroll
      for (int v = 0; v < 4; v++)
        s4[mi][v] += __shfl_xor(s4[mi][v], off);
  if (rr == 0) {
#pragma unroll
    for (int mi = 0; mi < 4; mi++)
#pragma unroll
      for (int v = 0; v < 4; v++)
        red[(wv << 6) + (mi << 4) + (q << 2) + v] = s4[mi][v];
  }
  __syncthreads();

  const float cdiff = bb2[1] - bb2[0];
  if (t < 64) {
    float s = red[t] + red[64 + t] + red[128 + t] + red[192 + t] + cdiff;
    scores[t] = s;
    if (fabsf(s) < MARGIN2) {
      int idx = atomicAdd(&nmarg, 1);
      mlist[idx] = t;
    }
  }
  __syncthreads();

  // exact fp32 recheck of marginal rows (expected ~0.1 per block)
  int nm = nmarg;
  for (int i = 0; i < nm; i++) {
    int row = mlist[i];
    float a0 = 0.f, a1 = 0.f;
    int j0 = t << 1;
    const float* xr = bd + (size_t)(m0 + row) * 256;
    for (int m = 0; m < 128; m++) {
      float x = xr[m];
      a0 = fmaf(x, Wb1[m * 512 + j0], a0);
      a1 = fmaf(x, Wb1[m * 512 + j0 + 1], a1);
    }
    float s = fmaxf(a0 + bb1[j0], 0.f) * (Wb2[j0 * 2 + 1] - Wb2[j0 * 2]) +
              fmaxf(a1 + bb1[j0 + 1], 0.f) * (Wb2[j0 * 2 + 3] - Wb2[j0 * 2 + 2]);
#pragma unroll
    for (int off = 1; off <= 32; off <<= 1) s += __shfl_xor(s, off);
    if (ln == 0) redw[wv] = s;
    __syncthreads();
    if (t == 0) scores[row] = redw[0] + redw[1] + redw[2] + redw[3] + cdiff;
    __syncthreads();
  }

  // rowmap placement (k1d logic inline)
  if (t < 64) {
    int sel = (scores[t] >= 0.f) ? 1 : 0;
    int slot = sel ? (NSLOTS - 1 - atomicAdd(&counters[2], 1))
                   : atomicAdd(&counters[1], 1);
    rowmap[slot] = m0 + t;
  }
}

// ---------------- K2: FUSED GEMM1+GEMM2 (unchanged from R8) ----------------
__global__ __launch_bounds__(256, 3) void k2_fused(
    const ushort* __restrict__ x2bf, const ushort* __restrict__ wl1t,
    const ushort* __restrict__ w2t, const float* __restrict__ bl1,
    const float* __restrict__ bl2, const int* __restrict__ rowmap,
    const int* __restrict__ counters, float* __restrict__ out) {
  __shared__ __align__(1024) ushort As[4096];     // x2 [64 r][64 k] / kstep
  __shared__ __align__(1024) ushort WtHs[16384];  // Wt[256][64] <-> Hs[64][256]
  __shared__ __align__(1024) ushort Ws[6144];     // W2 [48][128 half]
  ushort* Wt = WtHs;
  ushort* Hs = WtHs;
  const int t = threadIdx.x, ln = t & 63, wv = t >> 6;
  const int ks2 = blockIdx.x;       // n-half 0,1
  const int m0 = blockIdx.y << 6;   // 64 slot-base
  const int q = ln >> 4, rr = ln & 15;
  const int r8 = ln >> 3, s8 = ln & 7;
  const int r4 = ln >> 4, s16 = ln & 15;
  const int c0 = counters[1];
  const int sel_blk = (m0 >= c0) ? 1 : 0;
  const int selbase = sel_blk * 48;

  int g_as[2];
#pragma unroll
  for (int ii = 0; ii < 2; ii++) {
    int g = rowmap[m0 + (((wv << 1) + ii) << 3) + r8];
    g_as[ii] = (g < 0) ? 0 : g;
  }

  f32x4 accP[3] = {};

  for (int nc = 0; nc < 4; nc++) {
    const int n0 = (ks2 << 10) + (nc << 8);

    f32x4 acc1[4][4] = {};
#pragma unroll 1
    for (int ks = 0; ks < 4; ks++) {
      const int kg = ks << 6;
#pragma unroll
      for (int ii = 0; ii < 2; ii++)
        GLD16(x2bf + (size_t)g_as[ii] * 256 + kg + ((s8 ^ r8) << 3),
              As + ((((wv << 1) + ii)) << 9));
#pragma unroll
      for (int ii = 0; ii < 8; ii++) {
        int inst = (wv << 3) + ii;
        int r = (inst << 3) + r8;
        GLD16(wl1t + (size_t)(n0 + r) * 256 + kg + ((s8 ^ r8) << 3),
              Wt + (inst << 9));
      }
      __syncthreads();
#pragma unroll
      for (int kk = 0; kk < 2; kk++) {
        int c = (kk << 2) + q;
        int sl = (c ^ (rr & 7)) << 3;
        bf16x8 af[4], bfv[4];
#pragma unroll
        for (int mi = 0; mi < 4; mi++)
          af[mi] = *(const bf16x8*)(Wt + (((wv << 6) + (mi << 4) + rr) << 6) + sl);
#pragma unroll
        for (int ni = 0; ni < 4; ni++)
          bfv[ni] = *(const bf16x8*)(As + (((ni << 4) + rr) << 6) + sl);
#pragma unroll
        for (int mi = 0; mi < 4; mi++)
#pragma unroll
          for (int ni = 0; ni < 4; ni++)
            acc1[mi][ni] = __builtin_amdgcn_mfma_f32_16x16x32_bf16(
                af[mi], bfv[ni], acc1[mi][ni], 0, 0, 0);
      }
      __syncthreads();
    }

#pragma unroll
    for (int mi = 0; mi < 4; mi++) {
      int p = (wv << 4) + (mi << 2) + q;
      float bias0 = bl1[n0 + (p << 2) + 0];
      float bias1 = bl1[n0 + (p << 2) + 1];
      float bias2 = bl1[n0 + (p << 2) + 2];
      float bias3 = bl1[n0 + (p << 2) + 3];
#pragma unroll
      for (int ni = 0; ni < 4; ni++) {
        int hsrow = (ni << 4) + rr;
        f32x4 a = acc1[mi][ni];
        ushort4 pk;
        pk.x = f2bf(fmaxf(a[0] + bias0, 0.f));
        pk.y = f2bf(fmaxf(a[1] + bias1, 0.f));
        pk.z = f2bf(fmaxf(a[2] + bias2, 0.f));
        pk.w = f2bf(fmaxf(a[3] + bias3, 0.f));
        *(ushort4*)(Hs + (hsrow << 8) + ((p ^ rr) << 2)) = pk;
      }
    }

#pragma unroll 1
    for (int h = 0; h < 2; h++) {
#pragma unroll
      for (int jj = 0; jj < 3; jj++) {
        int inst = wv * 3 + jj;
        int r = (inst << 2) + r4;
        int c = s16 ^ (r & 15);
        GLD16(w2t + (size_t)(selbase + r) * 2048 + n0 + (h << 7) + (c << 3),
              Ws + (inst << 9));
      }
      __syncthreads();
#pragma unroll
      for (int kk = 0; kk < 4; kk++) {
        int p0 = (h << 5) + (kk << 3) + (q << 1);
        int hrow = (wv << 4) + rr;
        union { ushort4 u[2]; bf16x8 v; } hu;
        hu.u[0] = *(const ushort4*)(Hs + (hrow << 8) + ((p0 ^ rr) << 2));
        hu.u[1] = *(const ushort4*)(Hs + (hrow << 8) + (((p0 + 1) ^ rr) << 2));
        int c = (kk << 2) + q;
#pragma unroll
        for (int ni = 0; ni < 3; ni++) {
          bf16x8 wb = *(const bf16x8*)(Ws + (((ni << 4) + rr) << 7) +
                                       ((c ^ rr) << 3));
          accP[ni] = __builtin_amdgcn_mfma_f32_16x16x32_bf16(
              hu.v, wb, accP[ni], 0, 0, 0);
        }
      }
      __syncthreads();
    }
  }

  {
    float b[3] = {0.f, 0.f, 0.f};
    if (ks2 == 0) {
#pragma unroll
      for (int ni = 0; ni < 3; ni++)
        b[ni] = bl2[sel_blk * 1488 + (ni << 4) + rr];
    }
#pragma unroll
    for (int v = 0; v < 4; v++) {
      int slot = m0 + (wv << 4) + (q << 2) + v;
      int orig = rowmap[slot];
      if (orig >= 0) {
        float* ob = out + (size_t)orig * 48 + rr;
        atomicAdd(ob, accP[0][v] + b[0]);
        atomicAdd(ob + 16, accP[1][v] + b[1]);
        atomicAdd(ob + 32, accP[2][v] + b[2]);
      }
    }
  }
}

extern "C" void kernel_launch(void* const* d_in, const int* in_sizes, int n_in,
                              void* d_out, int out_size, void* d_ws, size_t ws_size,
                              hipStream_t stream) {
  const float* bd  = (const float*)d_in[0];
  const float* Wl1 = (const float*)d_in[1];
  const float* bl1 = (const float*)d_in[2];
  const float* Wl2 = (const float*)d_in[3];
  const float* bl2 = (const float*)d_in[4];
  const float* Wb1 = (const float*)d_in[5];
  const float* bb1 = (const float*)d_in[6];
  const float* Wb2 = (const float*)d_in[7];
  const float* bb2 = (const float*)d_in[8];

  char* ws = (char*)d_ws;
  ushort* x2bf  = (ushort*)(ws);                  // 16384*256*2 = 8,388,608
  ushort* wl1t  = (ushort*)(ws + 8388608);        // 2048*256*2  = 1,048,576
  ushort* w2t   = (ushort*)(ws + 9437184);        // 96*2048*2   =   393,216
  ushort* x1lo  = (ushort*)(ws + 9830400);        // 16384*128*2 = 4,194,304
  ushort* wb1t  = (ushort*)(ws + 14024704);       // 512*128*2   =   131,072
  ushort* wb1lo = (ushort*)(ws + 14155776);       // 512*128*2   =   131,072
  int*    rowmap= (int*)(ws + 14286848);          // 16448*4     =    65,792
  int*    counters=(int*)(ws + 14352640);         // 8*4
  float*  outp  = (float*)d_out;

  k0_convert<<<dim3(4096), dim3(256), 0, stream>>>(
      bd, Wl1, Wl2, Wb1, x2bf, wl1t, w2t, wb1t, wb1lo, x1lo,
      rowmap, counters, outp);
  k1_router<<<dim3(256), dim3(256), 0, stream>>>(
      x2bf, x1lo, wb1t, wb1lo, bd, Wb1, Wb2, bb1, bb2, rowmap, counters);
  k2_fused<<<dim3(2, 257), dim3(256), 0, stream>>>(
      x2bf, wl1t, w2t, bl1, bl2, rowmap, counters, outp);
}